// Round 8
// baseline (154.379 us; speedup 1.0000x reference)
//
#include <hip/hip_runtime.h>
#include <hip/hip_bf16.h>
#include <stdint.h>

#define NPTS 81920
#define CIN  64
#define COUT 128
#define BATCH 4
#define KNB  10
#define NT   32       // n-rows per block

typedef __attribute__((ext_vector_type(8)))  short bf16x8;
typedef __attribute__((ext_vector_type(16))) float f32x16;

static __device__ __forceinline__ unsigned short f2bf(float f) {
    unsigned int u = __float_as_uint(f);
    u += 0x7fffu + ((u >> 16) & 1u);      // RNE, finite inputs
    return (unsigned short)(u >> 16);
}

static __device__ __forceinline__ void gload16(const void* g, void* l) {
    __builtin_amdgcn_global_load_lds(
        (const __attribute__((address_space(1))) unsigned int*)g,
        (__attribute__((address_space(3))) unsigned int*)l, 16, 0, 0);
}

// ---------------------------------------------------------------------------
// Kernel 1: x (B, CIN, N) f32  ->  xT (N, B, CIN) bf16
//   one gather row per point = 4 batches x 128 B = 512 B contiguous.
// ---------------------------------------------------------------------------
__global__ __launch_bounds__(256) void k_transpose(const float* __restrict__ x,
                                                   unsigned short* __restrict__ xT) {
    const int m = blockIdx.x * 256 + threadIdx.x;
    const int b = blockIdx.y;
    const float* xb = x + (size_t)b * CIN * NPTS + m;

    unsigned int v[CIN / 2];
    #pragma unroll
    for (int i = 0; i < CIN / 2; ++i) {
        float f0 = __builtin_nontemporal_load(&xb[(size_t)(2 * i) * NPTS]);
        float f1 = __builtin_nontemporal_load(&xb[(size_t)(2 * i + 1) * NPTS]);
        v[i] = (unsigned int)f2bf(f0) | ((unsigned int)f2bf(f1) << 16);
    }
    uint4* dst = (uint4*)(xT + ((size_t)m * BATCH + b) * CIN);
    #pragma unroll
    for (int i = 0; i < 8; ++i) {
        uint4 w; w.x = v[4*i]; w.y = v[4*i+1]; w.z = v[4*i+2]; w.w = v[4*i+3];
        dst[i] = w;                                   // 128 B contiguous per lane
    }
}

// ---------------------------------------------------------------------------
// Kernel 2: W (COUT, CIN, KNB) f32 -> Wb bf16 in 32x32x16 A-fragment order:
//   e = ((sg*4 + f)*64 + lane)*8 + j   (sg = 0..39 ksteps of 16, f = o-frag)
//   o = 32*f + (lane&31);  ck = sg*16 + 8*(lane>>5) + j;
//   kn = ck>>6; c = ck&63;  value = W[(o*CIN + c)*KNB + kn]
// ---------------------------------------------------------------------------
__global__ __launch_bounds__(256) void k_wconv(const float* __restrict__ W,
                                               unsigned short* __restrict__ Wb) {
    const int e  = blockIdx.x * 256 + threadIdx.x;   // 0 .. 81919
    const int j  = e & 7;
    const int l  = (e >> 3) & 63;
    const int f  = (e >> 9) & 3;
    const int sg = e >> 11;                          // 0 .. 39
    const int o  = 32 * f + (l & 31);
    const int ck = sg * 16 + 8 * (l >> 5) + j;
    const int kn = ck >> 6;
    const int c  = ck & 63;
    Wb[e] = f2bf(W[(o * CIN + c) * KNB + kn]);
}

// ---------------------------------------------------------------------------
// Main: block = 8 waves (512 thr), NT=32 rows, ALL 4 batches in-block.
// Wave wv: op = wv&1 (o-frag pair {2op, 2op+1}), b = wv>>1 (one batch).
// Per wave: acc[p] = 2 x f32x16 = 32 AGPR; B-frag reused across 2 o-frags.
// mfma_32x32x16. LDS: smem[buf][32 rows][512 B], row-contiguous staging with
// 16B-granule XOR source pre-swizzle (rule #21), 4-way read conflict accepted.
//
// R8 change: __launch_bounds__(512,6) — R6's (512,4) capped residency at
// 2 blocks/CU (43% occ); gather is latency/TLP-bound, so allow 3 blocks/CU
// (24 waves, 75%). VGPR budget 512/6 = 85 unified; R6 used ~80 — fits.
// ---------------------------------------------------------------------------
__global__ __launch_bounds__(512, 6) void k_main(const unsigned short* __restrict__ xT,
                                                 const unsigned short* __restrict__ Wb,
                                                 const float* __restrict__ bias,
                                                 const int* __restrict__ idx,
                                                 float* __restrict__ out) {
    __shared__ char smem[2][NT * 512];

    const int t    = threadIdx.x;
    const int lane = t & 63;
    const int wv   = t >> 6;                 // 0..7
    const int op   = wv & 1;                 // o-pair: frags {2op, 2op+1}
    const int b    = wv >> 1;                // batch 0..3
    const int hw   = lane >> 5;              // half-wave
    const int l31  = lane & 31;
    const int nb   = blockIdx.x * NT;

    const char* xb = (const char*)xT;
    const bf16x8* wbase = (const bf16x8*)Wb;

    // Precompute stage byte-offsets (statically indexed -> registers).
    // Wave stages rows 4wv .. 4wv+3: inst i covers rows {4wv+2i, 4wv+2i+1},
    // lane's row = 4wv+2i+hw, lane reads source granule (l31 ^ (row&7)).
    int soff[KNB][2];
    #pragma unroll
    for (int k = 0; k < KNB; ++k) {
        #pragma unroll
        for (int i = 0; i < 2; ++i) {
            const int row = (wv << 2) + (i << 1) + hw;
            const int r   = idx[(nb + row) * KNB + k];
            soff[k][i] = r * 512 + ((l31 ^ (row & 7)) << 4);
        }
    }

    f32x16 acc[2];
    #pragma unroll
    for (int p = 0; p < 2; ++p)
        #pragma unroll
        for (int r = 0; r < 16; ++r) acc[p][r] = 0.f;

    #define STAGE(kk, buf)                                                      \
        {                                                                       \
            _Pragma("unroll")                                                   \
            for (int i = 0; i < 2; ++i) {                                       \
                gload16(xb + soff[kk][i],                                       \
                        &smem[buf][(((wv << 2) + (i << 1))) << 9]);             \
            }                                                                   \
        }

    STAGE(0, 0);
    __syncthreads();                          // stage(0) landed (vmcnt drain)

    #pragma unroll
    for (int k = 0; k < KNB; ++k) {
        if (k + 1 < KNB) STAGE(k + 1, (k + 1) & 1);   // overlaps this k's work

        // A-fragments: 2 o-frags x 4 ksteps, 1 KB each from Wb (L1/L2-hot).
        bf16x8 a[2][4];
        #pragma unroll
        for (int p = 0; p < 2; ++p)
            #pragma unroll
            for (int ks = 0; ks < 4; ++ks)
                a[p][ks] = wbase[((k * 4 + ks) * 4 + (op * 2 + p)) * 64 + lane];

        const char* sb = smem[k & 1];
        #pragma unroll
        for (int ks = 0; ks < 4; ++ks) {
            const int g    = b * 8 + ks * 2 + hw;            // true 16B granule
            const int byte = (g ^ (l31 & 7)) << 4;           // XOR-swizzled slot
            const bf16x8 bf = *(const bf16x8*)(sb + l31 * 512 + byte);
            #pragma unroll
            for (int p = 0; p < 2; ++p)
                acc[p] = __builtin_amdgcn_mfma_f32_32x32x16_bf16(
                    a[p][ks], bf, acc[p], 0, 0, 0);
        }
        __syncthreads();                      // stage(k+1) landed + WAR fence
    }
    #undef STAGE

    // Epilogue: o = 32*(2op+p) + (r&3) + 8*(r>>2) + 4*hw; n = nb + l31.
    const int n = nb + l31;
    #pragma unroll
    for (int p = 0; p < 2; ++p) {
        #pragma unroll
        for (int r = 0; r < 16; ++r) {
            const int o = 32 * (op * 2 + p) + (r & 3) + 8 * (r >> 2) + 4 * hw;
            const float v = acc[p][r] + bias[o];
            __builtin_nontemporal_store(v, &out[(size_t)(b * COUT + o) * NPTS + n]);
        }
    }
}

// ---------------------------------------------------------------------------
extern "C" void kernel_launch(void* const* d_in, const int* in_sizes, int n_in,
                              void* d_out, int out_size, void* d_ws, size_t ws_size,
                              hipStream_t stream) {
    const float* x    = (const float*)d_in[0];
    const int*   idx  = (const int*)d_in[1];
    const float* W    = (const float*)d_in[2];
    const float* bias = (const float*)d_in[3];
    float* out = (float*)d_out;

    // Workspace layout: xT bf16 (N*B*CIN*2 = 41.94 MB), then Wb bf16 (160 KB).
    unsigned short* xT = (unsigned short*)d_ws;
    unsigned short* Wb = (unsigned short*)((char*)d_ws + (size_t)BATCH * NPTS * CIN * 2);

    k_transpose<<<dim3(NPTS / 256, BATCH), 256, 0, stream>>>(x, xT);
    k_wconv<<<dim3((COUT * KNB * CIN) / 256), 256, 0, stream>>>(W, Wb);
    k_main<<<dim3(NPTS / NT), 512, 0, stream>>>(xT, Wb, bias, idx, out);
}

// Round 9
// 133.869 us; speedup vs baseline: 1.1532x; 1.1532x over previous
//
#include <hip/hip_runtime.h>
#include <hip/hip_bf16.h>
#include <stdint.h>

#define NPTS 81920
#define CIN  64
#define COUT 128
#define BATCH 4
#define KNB  10
#define NT   32       // n-rows per block

typedef __attribute__((ext_vector_type(8)))  short bf16x8;
typedef __attribute__((ext_vector_type(16))) float f32x16;

static __device__ __forceinline__ unsigned short f2bf(float f) {
    unsigned int u = __float_as_uint(f);
    u += 0x7fffu + ((u >> 16) & 1u);      // RNE, finite inputs
    return (unsigned short)(u >> 16);
}

// ---------------------------------------------------------------------------
// Kernel 1: x (B, CIN, N) f32  ->  xT (N, B, CIN) bf16
//   one gather row per point = 4 batches x 128 B = 512 B contiguous.
// ---------------------------------------------------------------------------
__global__ __launch_bounds__(256) void k_transpose(const float* __restrict__ x,
                                                   unsigned short* __restrict__ xT) {
    const int m = blockIdx.x * 256 + threadIdx.x;
    const int b = blockIdx.y;
    const float* xb = x + (size_t)b * CIN * NPTS + m;

    unsigned int v[CIN / 2];
    #pragma unroll
    for (int i = 0; i < CIN / 2; ++i) {
        float f0 = __builtin_nontemporal_load(&xb[(size_t)(2 * i) * NPTS]);
        float f1 = __builtin_nontemporal_load(&xb[(size_t)(2 * i + 1) * NPTS]);
        v[i] = (unsigned int)f2bf(f0) | ((unsigned int)f2bf(f1) << 16);
    }
    uint4* dst = (uint4*)(xT + ((size_t)m * BATCH + b) * CIN);
    #pragma unroll
    for (int i = 0; i < 8; ++i) {
        uint4 w; w.x = v[4*i]; w.y = v[4*i+1]; w.z = v[4*i+2]; w.w = v[4*i+3];
        dst[i] = w;                                   // 128 B contiguous per lane
    }
}

// ---------------------------------------------------------------------------
// Kernel 2: W (COUT, CIN, KNB) f32 -> Wb bf16 in 32x32x16 A-fragment order:
//   e = ((sg*4 + f)*64 + lane)*8 + j   (sg = 0..39 ksteps of 16, f = o-frag)
//   o = 32*f + (lane&31);  ck = sg*16 + 8*(lane>>5) + j;
//   kn = ck>>6; c = ck&63;  value = W[(o*CIN + c)*KNB + kn]
// ---------------------------------------------------------------------------
__global__ __launch_bounds__(256) void k_wconv(const float* __restrict__ W,
                                               unsigned short* __restrict__ Wb) {
    const int e  = blockIdx.x * 256 + threadIdx.x;   // 0 .. 81919
    const int j  = e & 7;
    const int l  = (e >> 3) & 63;
    const int f  = (e >> 9) & 3;
    const int sg = e >> 11;                          // 0 .. 39
    const int o  = 32 * f + (l & 31);
    const int ck = sg * 16 + 8 * (l >> 5) + j;
    const int kn = ck >> 6;
    const int c  = ck & 63;
    Wb[e] = f2bf(W[(o * CIN + c) * KNB + kn]);
}

// ---------------------------------------------------------------------------
// Main: block = 8 waves (512 thr), NT=32 rows, ALL 4 batches in-block.
// Wave wv: op = wv&3 (one 32-o frag), bq = wv>>2 (batches {2bq, 2bq+1}).
// Per wave: acc[bb] = 2 x f32x16 = 32 AGPR; A-frag reused across 2 batches.
//
// R9 structure (T14 reg-staging, no global_load_lds):
//   iter k: waitcnt(vm 0, lgkm 0); s_barrier;
//           ds_write B(k+1) (regs loaded iter k-1);
//           issue A(k+1) reg-loads + B(k+2) reg-loads;
//           compute(k): 8 x {ds_read_b128 + mfma_32x32x16}.
//   Gather B(k+2) gets ~2 iterations of flight before its LDS write; A 1 iter.
//   Single vmcnt(0) per iter only retires loads issued a full iter earlier.
//
// LDS: 2 buffers x 16 KB, granule-major: row R's 16B-granule G stored at
//   G*512 + ((R^G)&31)*16. Reads (G fixed, 32 lanes R=l31): permuted
//   contiguous 512 B  -> 0 bank conflicts (R4-measured pattern).
//   Writes (R fixed, G=l31): ~4-way, only 2 insts/wave/iter — negligible.
// ---------------------------------------------------------------------------
__global__ __launch_bounds__(512, 4) void k_main(const unsigned short* __restrict__ xT,
                                                 const unsigned short* __restrict__ Wb,
                                                 const float* __restrict__ bias,
                                                 const int* __restrict__ idx,
                                                 float* __restrict__ out) {
    __shared__ char smem[2][NT * 512];

    const int t    = threadIdx.x;
    const int lane = t & 63;
    const int wv   = t >> 6;                 // 0..7
    const int op   = wv & 3;                 // o-frag (32 o)
    const int bq   = wv >> 2;                // batch pair {2bq, 2bq+1}
    const int hw   = lane >> 5;              // half-wave
    const int l31  = lane & 31;
    const int nb   = blockIdx.x * NT;

    const char* xb = (const char*)xT;
    const bf16x8* wbase = (const bf16x8*)Wb;

    // Stage offsets: wave stages rows 4wv..4wv+3; inst i covers rows
    // {4wv+2i, 4wv+2i+1}; lane's row = 4wv+2i+hw, granule l31.
    const int row0 = (wv << 2) + hw;         // i=0 row
    const int row1 = row0 + 2;               // i=1 row
    int soff[KNB][2];
    #pragma unroll
    for (int k = 0; k < KNB; ++k) {
        soff[k][0] = idx[(nb + row0) * KNB + k] * 512;
        soff[k][1] = idx[(nb + row1) * KNB + k] * 512;
    }
    // ds_write byte offsets (constant per lane)
    const int wo0 = (l31 << 9) + (((row0 ^ l31) & 31) << 4);
    const int wo1 = (l31 << 9) + (((row1 ^ l31) & 31) << 4);

    f32x16 acc[2];
    #pragma unroll
    for (int bb = 0; bb < 2; ++bb)
        #pragma unroll
        for (int r = 0; r < 16; ++r) acc[bb][r] = 0.f;

    // ---- prologue: B(0) -> regs -> LDS buf0; issue A(0), B(1) ----
    uint4 b0 = *(const uint4*)(xb + soff[0][0] + l31 * 16);
    uint4 b1 = *(const uint4*)(xb + soff[0][1] + l31 * 16);
    asm volatile("s_waitcnt vmcnt(0)" ::: "memory");
    *(uint4*)(smem[0] + wo0) = b0;
    *(uint4*)(smem[0] + wo1) = b1;

    bf16x8 a[4], an[4];
    #pragma unroll
    for (int ks = 0; ks < 4; ++ks)
        a[ks] = wbase[((0 * 4 + ks) * 4 + op) * 64 + lane];
    uint4 bn0 = *(const uint4*)(xb + soff[1][0] + l31 * 16);
    uint4 bn1 = *(const uint4*)(xb + soff[1][1] + l31 * 16);

    // ---- main loop ----
    #pragma unroll
    for (int k = 0; k < KNB; ++k) {
        // Retire loads issued last iter (a full iteration of flight) and
        // drain ds ops; publish buf (k&1) writes + WAR-fence buf (k+1)&1.
        asm volatile("s_waitcnt vmcnt(0) lgkmcnt(0)" ::: "memory");
        __builtin_amdgcn_s_barrier();

        if (k + 1 < KNB) {                   // LDS-write next tile from regs
            char* d = smem[(k + 1) & 1];
            *(uint4*)(d + wo0) = bn0;
            *(uint4*)(d + wo1) = bn1;
            #pragma unroll
            for (int ks = 0; ks < 4; ++ks)   // prefetch A(k+1)
                an[ks] = wbase[(((k + 1) * 4 + ks) * 4 + op) * 64 + lane];
        }
        if (k + 2 < KNB) {                   // issue gather B(k+2) -> regs
            bn0 = *(const uint4*)(xb + soff[k + 2][0] + l31 * 16);
            bn1 = *(const uint4*)(xb + soff[k + 2][1] + l31 * 16);
        }

        // compute(k): granule g = (2bq+bb)*8 + 2ks + hw; row wanted = l31.
        const char* sb = smem[k & 1];
        #pragma unroll
        for (int ks = 0; ks < 4; ++ks) {
            #pragma unroll
            for (int bb = 0; bb < 2; ++bb) {
                const int g = (bq * 2 + bb) * 8 + ks * 2 + hw;
                const bf16x8 bf =
                    *(const bf16x8*)(sb + (g << 9) + (((l31 ^ g) & 31) << 4));
                acc[bb] = __builtin_amdgcn_mfma_f32_32x32x16_bf16(
                    a[ks], bf, acc[bb], 0, 0, 0);
            }
        }
        #pragma unroll
        for (int ks = 0; ks < 4; ++ks) a[ks] = an[ks];
    }

    // Epilogue: o = 32*op + (r&3) + 8*(r>>2) + 4*hw; n = nb + l31; b = 2bq+bb.
    const int n = nb + l31;
    #pragma unroll
    for (int bb = 0; bb < 2; ++bb) {
        const int b = bq * 2 + bb;
        #pragma unroll
        for (int r = 0; r < 16; ++r) {
            const int o = 32 * op + (r & 3) + 8 * (r >> 2) + 4 * hw;
            const float v = acc[bb][r] + bias[o];
            __builtin_nontemporal_store(v, &out[(size_t)(b * COUT + o) * NPTS + n]);
        }
    }
}

// ---------------------------------------------------------------------------
extern "C" void kernel_launch(void* const* d_in, const int* in_sizes, int n_in,
                              void* d_out, int out_size, void* d_ws, size_t ws_size,
                              hipStream_t stream) {
    const float* x    = (const float*)d_in[0];
    const int*   idx  = (const int*)d_in[1];
    const float* W    = (const float*)d_in[2];
    const float* bias = (const float*)d_in[3];
    float* out = (float*)d_out;

    // Workspace layout: xT bf16 (N*B*CIN*2 = 41.94 MB), then Wb bf16 (160 KB).
    unsigned short* xT = (unsigned short*)d_ws;
    unsigned short* Wb = (unsigned short*)((char*)d_ws + (size_t)BATCH * NPTS * CIN * 2);

    k_transpose<<<dim3(NPTS / 256, BATCH), 256, 0, stream>>>(x, xT);
    k_wconv<<<dim3((COUT * KNB * CIN) / 256), 256, 0, stream>>>(W, Wb);
    k_main<<<dim3(NPTS / NT), 512, 0, stream>>>(xT, Wb, bias, idx, out);
}